// Round 18
// baseline (186.747 us; speedup 1.0000x reference)
//
#include <hip/hip_runtime.h>

// NSA constants
#define NCMP 127
#define SCALE 0.08838834764831845f
#define QSCALE (0.08838834764831845f * 1.4426950408889634f)  // SCALE * log2(e)

typedef __attribute__((ext_vector_type(8))) short bf16x8;
typedef __attribute__((ext_vector_type(4))) float f32x4;

__device__ __forceinline__ unsigned short f2bf(float x) {
    union { float f; unsigned u; } a; a.f = x;
    unsigned r = a.u + 0x7fffu + ((a.u >> 16) & 1u);
    return (unsigned short)(r >> 16);
}
__device__ __forceinline__ float bf2f(unsigned short s) {
    union { unsigned u; float f; } x; x.u = ((unsigned)s) << 16; return x.f;
}
__device__ __forceinline__ float dot4(float4 a, float4 b) {
    return a.x * b.x + a.y * b.y + a.z * b.z + a.w * b.w;
}
__device__ __forceinline__ void gload_lds16(const void* g, void* l) {
    __builtin_amdgcn_global_load_lds(
        (const __attribute__((address_space(1))) unsigned int*)g,
        (__attribute__((address_space(3))) unsigned int*)l, 16, 0, 0);
}

// ---- Kernel P: fused prep — convert (bid<64) + compress (bid>=64) ----
__global__ __launch_bounds__(256) void k_prep(const float* __restrict__ k,
                                              const float* __restrict__ v,
                                              const float* __restrict__ wk,
                                              const float* __restrict__ wv,
                                              float* __restrict__ ck,
                                              float* __restrict__ cv,
                                              unsigned short* __restrict__ kswz,
                                              unsigned short* __restrict__ vswz) {
    __shared__ float shbuf[4128];
    int tid = threadIdx.x;

    if (blockIdx.x < 64) {
        // ================= convert =================
        unsigned short* vl = (unsigned short*)shbuf;   // [32][132]
        int wgid = blockIdx.x;
        int b = wgid >> 1, half = wgid & 1;
        int r0 = b * 64 + half * 32;

        #pragma unroll
        for (int it = 0; it < 4; ++it) {
            int idx = it * 1024 + tid * 4;
            int row = r0 + (idx >> 7), d = idx & 127;
            float4 x = *reinterpret_cast<const float4*>(k + r0 * 128 + idx);
            unsigned short o[4] = {f2bf(x.x), f2bf(x.y), f2bf(x.z), f2bf(x.w)};
            char* dst = (char*)kswz + row * 256 + ((d * 2) ^ ((row & 7) << 4));
            *reinterpret_cast<unsigned long long*>(dst) = *reinterpret_cast<unsigned long long*>(o);
        }
        #pragma unroll
        for (int it = 0; it < 4; ++it) {
            int idx = it * 1024 + tid * 4;
            int pl = idx >> 7, d = idx & 127;
            float4 x = *reinterpret_cast<const float4*>(v + r0 * 128 + idx);
            unsigned short o[4] = {f2bf(x.x), f2bf(x.y), f2bf(x.z), f2bf(x.w)};
            *reinterpret_cast<unsigned long long*>(&vl[pl * 132 + d]) =
                *reinterpret_cast<unsigned long long*>(o);
        }
        __syncthreads();
        #pragma unroll
        for (int it = 0; it < 2; ++it) {
            int task = it * 256 + tid;
            int d = task >> 2, cjs = task & 3;
            int src_chunk = half * 4 + cjs;
            int dst_chunk = src_chunk ^ (d & 7);
            union { unsigned short s[8]; uint4 q; } u;
            #pragma unroll
            for (int i = 0; i < 8; ++i) u.s[i] = vl[(cjs * 8 + i) * 132 + d];
            char* dst = (char*)vswz + b * 16384 + d * 128 + dst_chunk * 16;
            *reinterpret_cast<uint4*>(dst) = u.q;
        }
    } else {
        // ================= compress =================
        float* blk = shbuf;
        float* gate = shbuf + 4096;
        int id = blockIdx.x - 64;
        int n = id >> 1;
        int which = id & 1;
        const float* src = which ? v : k;
        const float* w   = which ? wv : wk;
        float* out       = which ? cv : ck;

        {
            const float4* sp = reinterpret_cast<const float4*>(src + n * 16 * 128);
            float4* bp = reinterpret_cast<float4*>(blk);
            #pragma unroll
            for (int i = 0; i < 4; ++i) bp[tid + 256 * i] = sp[tid + 256 * i];
        }
        __syncthreads();
        {
            int j = tid >> 3, sub = tid & 7;
            const float4* wp = reinterpret_cast<const float4*>(w + j * 4096);
            const float4* bp = reinterpret_cast<const float4*>(blk);
            float s0 = 0.f, s1 = 0.f, s2 = 0.f, s3 = 0.f;
            for (int i = sub * 4; i < 1024; i += 32) {
                float4 w0 = wp[i], w1 = wp[i + 1], w2 = wp[i + 2], w3 = wp[i + 3];
                s0 += dot4(bp[i], w0);
                s1 += dot4(bp[i + 1], w1);
                s2 += dot4(bp[i + 2], w2);
                s3 += dot4(bp[i + 3], w3);
            }
            float s = (s0 + s1) + (s2 + s3);
            s += __shfl_xor(s, 1);
            s += __shfl_xor(s, 2);
            s += __shfl_xor(s, 4);
            if (sub == 0) gate[j] = s;
        }
        __syncthreads();
        if (tid < 32) {
            float gv = gate[tid];
            float m = gv;
            #pragma unroll
            for (int off = 16; off > 0; off >>= 1) m = fmaxf(m, __shfl_xor(m, off));
            float e = expf(gv - m);
            float ss = e;
            #pragma unroll
            for (int off = 16; off > 0; off >>= 1) ss += __shfl_xor(ss, off);
            gate[tid] = e / ss;
        }
        __syncthreads();
        if (tid < 128) {
            float acc = 0.f;
            #pragma unroll
            for (int kx = 0; kx < 32; ++kx) acc += gate[kx] * blk[kx * 128 + tid];
            out[n * 128 + tid] = acc;
        }
    }
}

// -------- Kernel C: fully-fused NSA per t-pair --------
__global__ __launch_bounds__(256, 2) void k_main(const float* __restrict__ q,
                                              const float* __restrict__ ck,
                                              const float* __restrict__ cv,
                                              const unsigned short* __restrict__ kswz,
                                              const unsigned short* __restrict__ vswz,
                                              const float* __restrict__ fw,
                                              float* __restrict__ out) {
    __shared__ float smemf[8192];             // 32KB: phase0 sc/pg/adj, tile, mrg
    __shared__ unsigned short ocmp[16 * 136];
    __shared__ unsigned int selm[2];
    __shared__ float mlbuf[4][16][2];
    char* smem = (char*)smemf;

    int bid = blockIdx.x;
    int pairidx = (bid < 512) ? (1023 - bid) : (bid - 512);
    int tp = pairidx * 2;

    int tid = threadIdx.x;
    int wv = tid >> 6, ln = tid & 63;
    int c = ln & 15, g = ln >> 4;
    bool is_sel = (wv < 2);
    int w = wv & 1;

    int th = tp + (c >> 3);
    int hh = c & 7;

    // ======== phase 0: compressed branch + top-k select ========
    float* sc   = smemf;                   // [16][132] f32
    float* pgb  = smemf + 16 * 132;        // [2][128]
    float* adjb = smemf + 16 * 132 + 256;  // [2][32]

    // 0a: scores — wave owns 4 rows, q in regs, each ck 64B load feeds 4 rows
    {
        int ds = ln & 7, ng = ln >> 3;     // 8 lanes per n, 8 n's per pass
        int d0 = ds * 16;
        float4 qr[4][4];
        #pragma unroll
        for (int rr = 0; rr < 4; ++rr) {
            int row = wv * 4 + rr;
            const float4* qp = reinterpret_cast<const float4*>(
                q + (tp + (row >> 3)) * 1024 + (row & 7) * 128 + d0);
            #pragma unroll
            for (int cc = 0; cc < 4; ++cc) qr[rr][cc] = qp[cc];
        }
        #pragma unroll 2
        for (int pass = 0; pass < 16; ++pass) {
            int n = pass * 8 + ng;
            if (n >= NCMP) continue;
            const float4* kp = reinterpret_cast<const float4*>(ck + n * 128 + d0);
            float4 k0 = kp[0], k1 = kp[1], k2 = kp[2], k3 = kp[3];
            float part[4];
            #pragma unroll
            for (int rr = 0; rr < 4; ++rr)
                part[rr] = dot4(qr[rr][0], k0) + dot4(qr[rr][1], k1) +
                           dot4(qr[rr][2], k2) + dot4(qr[rr][3], k3);
            #pragma unroll
            for (int off = 1; off < 8; off <<= 1)
                #pragma unroll
                for (int rr = 0; rr < 4; ++rr) part[rr] += __shfl_xor(part[rr], off);
            if (ds == 0) {
                #pragma unroll
                for (int rr = 0; rr < 4; ++rr)
                    sc[(wv * 4 + rr) * 132 + n] = part[rr] * SCALE;
            }
        }
    }
    __syncthreads();
    // 0b: masked softmax per row (16 lanes/row)
    {
        int r = tid >> 4, nl = tid & 15;
        int t = tp + (r >> 3);
        int nvalid = (t >= 31) ? (((t - 31) >> 4) + 1) : 0;
        if (nvalid > NCMP) nvalid = NCMP;
        float* row = sc + r * 132;
        float m = -3e38f;
        for (int n = nl; n < nvalid; n += 16) m = fmaxf(m, row[n]);
        m = fmaxf(m, __shfl_xor(m, 1));
        m = fmaxf(m, __shfl_xor(m, 2));
        m = fmaxf(m, __shfl_xor(m, 4));
        m = fmaxf(m, __shfl_xor(m, 8));
        float ss = 0.f;
        for (int n = nl; n < 128; n += 16) {
            float e = (n < nvalid) ? expf(row[n] - m) : 0.f;
            ss += e;
            row[n] = e;
        }
        ss += __shfl_xor(ss, 1);
        ss += __shfl_xor(ss, 2);
        ss += __shfl_xor(ss, 4);
        ss += __shfl_xor(ss, 8);
        float inv = (ss > 0.f) ? 1.f / ss : 0.f;
        for (int n = nl; n < 128; n += 16) row[n] *= inv;
    }
    __syncthreads();
    // 0c: head-sum pg
    {
        int tl = tid >> 7, n = tid & 127;
        if (n < NCMP) {
            float s = 0.f;
            #pragma unroll
            for (int h = 0; h < 8; ++h) s += sc[(tl * 8 + h) * 132 + n];
            pgb[tl * 128 + n] = s;
        }
    }
    __syncthreads();
    // 0d: select-block scores + causal/forced adjust
    if (tid < 64) {
        int tl = tid >> 5, s32 = tid & 31;
        float s = 0.f;
        #pragma unroll
        for (int j = 0; j < 4; ++j) {
            int n = s32 * 4 + j;
            if (n < NCMP) s += pgb[tl * 128 + n];
        }
        int qblk = (tp + tl) >> 6;
        adjb[tl * 32 + s32] = (s32 > qblk) ? -1e30f
                            : s + ((s32 == 0 || s32 > qblk - 2) ? 1e30f : 0.f);
    }
    __syncthreads();
    // 0e: wave0 top-16; all waves compute o_cmp (cv load shared across 4 rows)
    if (wv == 0) {
        int grp = ln >> 5, s32 = ln & 31;
        float val = adjb[grp * 32 + s32];
        unsigned int msk = 0u;
        for (int it = 0; it < 16; ++it) {
            float bv = val; int bi = s32;
            #pragma unroll
            for (int off = 1; off < 32; off <<= 1) {
                float ov = __shfl_xor(bv, off);
                int oi = __shfl_xor(bi, off);
                if (ov > bv || (ov == bv && oi < bi)) { bv = ov; bi = oi; }
            }
            if (bv <= -5e29f) break;
            msk |= 1u << bi;
            if (s32 == bi) val = -2e38f;
        }
        if (s32 == 0) selm[grp] = msk;
    }
    {
        int d = ln * 2;
        int t = tp + (wv >> 1);            // rows wv*4..wv*4+3 share the same t
        int nv = (t >= 31) ? (((t - 31) >> 4) + 1) : 0;
        if (nv > NCMP) nv = NCMP;
        float a0[4] = {0.f, 0.f, 0.f, 0.f};
        float a1[4] = {0.f, 0.f, 0.f, 0.f};
        const float* scb = sc + (wv * 4) * 132;
        for (int n = 0; n < nv; ++n) {
            float2 vvv = *reinterpret_cast<const float2*>(cv + n * 128 + d);
            #pragma unroll
            for (int rr = 0; rr < 4; ++rr) {
                float p = scb[rr * 132 + n];
                a0[rr] += p * vvv.x;
                a1[rr] += p * vvv.y;
            }
        }
        #pragma unroll
        for (int rr = 0; rr < 4; ++rr) {
            unsigned int wrd = (unsigned int)f2bf(a0[rr]) | ((unsigned int)f2bf(a1[rr]) << 16);
            *reinterpret_cast<unsigned int*>(&ocmp[(wv * 4 + rr) * 136 + d]) = wrd;
        }
    }
    __syncthreads();
    unsigned int sm0 = selm[0], sm1 = selm[1];

    // Q fragments for the block loop (built AFTER phase 0 — not live through it)
    bf16x8 qf[4];
    {
        const float* qp = q + th * 1024 + hh * 128;
        #pragma unroll
        for (int ks = 0; ks < 4; ++ks) {
            int d0 = ks * 32 + g * 8;
            float4 x = *reinterpret_cast<const float4*>(qp + d0);
            float4 y = *reinterpret_cast<const float4*>(qp + d0 + 4);
            bf16x8 f;
            f[0]=(short)f2bf(x.x*QSCALE); f[1]=(short)f2bf(x.y*QSCALE); f[2]=(short)f2bf(x.z*QSCALE); f[3]=(short)f2bf(x.w*QSCALE);
            f[4]=(short)f2bf(y.x*QSCALE); f[5]=(short)f2bf(y.y*QSCALE); f[6]=(short)f2bf(y.z*QSCALE); f[7]=(short)f2bf(y.w*QSCALE);
            qf[ks] = f;
        }
    }

    // ======== block loop (identical to R13-R15) ========
    unsigned int sm_wave = sm0 | sm1;
    unsigned int smc = (c >> 3) ? sm1 : sm0;

    float m_run = -1e30f, l_run = 0.f;
    f32x4 o_acc[8];
    #pragma unroll
    for (int dt = 0; dt < 8; ++dt) o_acc[dt] = (f32x4){0.f, 0.f, 0.f, 0.f};

    int qblk_max = (tp + 1) >> 6;
    int wlo = (tp >= 575) ? (((tp - 575) >> 6) + 1) : 0;
    unsigned int all = (qblk_max >= 31) ? 0xFFFFFFFFu : ((1u << (qblk_max + 1)) - 1u);
    unsigned int wmask = all & ~((1u << wlo) - 1u);
    unsigned int mm = (sm_wave & all) | wmask;

    int srcA = ((g & 1) << 5) + c;
    int srcB = srcA + 16;
    bool hi = (g >= 2);

    auto stage = [&](int b) {
        const char* ks = (const char*)kswz + b * 16384;
        const char* vs = (const char*)vswz + b * 16384;
        char* kd = smem;
        char* vd = smem + 16384;
        int lo = wv * 1024;
        int so = lo + ln * 16;
        #pragma unroll
        for (int j = 0; j < 4; ++j) {
            gload_lds16(ks + j * 4096 + so, kd + j * 4096 + lo);
            gload_lds16(vs + j * 4096 + so, vd + j * 4096 + lo);
        }
    };

    auto compute = [&](int b) {
        const char* kl = smem;
        const char* vl = smem + 16384;
        int z = (c & 7) << 4;

        f32x4 sacc[4];
        #pragma unroll
        for (int nt = 0; nt < 4; ++nt) {
            f32x4 acc = (f32x4){0.f, 0.f, 0.f, 0.f};
            #pragma unroll
            for (int ks = 0; ks < 4; ++ks) {
                bf16x8 kf = *reinterpret_cast<const bf16x8*>(
                    kl + (nt * 16 + c) * 256 + ((ks * 64 + g * 16) ^ z));
                acc = __builtin_amdgcn_mfma_f32_16x16x32_bf16(kf, qf[ks], acc, 0, 0, 0);
            }
            sacc[nt] = acc;
        }

        bool selbit = (smc >> b) & 1u;
        float mloc = -1e30f;
        #pragma unroll
        for (int nt = 0; nt < 4; ++nt) {
            #pragma unroll
            for (int i = 0; i < 4; ++i) {
                int pos = b * 64 + nt * 16 + g * 4 + i;
                bool val;
                if (is_sel) val = selbit && (pos <= th);
                else        val = (pos <= th) && (pos + 512 > th);
                float s = val ? sacc[nt][i] : -1e30f;
                sacc[nt][i] = s;
                mloc = fmaxf(mloc, s);
            }
        }
        mloc = fmaxf(mloc, __shfl_xor(mloc, 16));
        mloc = fmaxf(mloc, __shfl_xor(mloc, 32));
        float mn = fmaxf(m_run, mloc);
        float al = exp2f(m_run - mn);

        float lsum = 0.f;
        #pragma unroll
        for (int nt = 0; nt < 4; ++nt) {
            #pragma unroll
            for (int i = 0; i < 4; ++i) {
                float s = sacc[nt][i];
                float p = (s > -5e29f) ? exp2f(s - mn) : 0.f;
                sacc[nt][i] = p;
                lsum += p;
            }
        }
        lsum += __shfl_xor(lsum, 16);
        lsum += __shfl_xor(lsum, 32);
        m_run = mn;
        l_run = l_run * al + lsum;

        if (__any(al != 1.f)) {
            #pragma unroll
            for (int dt = 0; dt < 8; ++dt)
                #pragma unroll
                for (int i = 0; i < 4; ++i)
                    o_acc[dt][i] *= al;
        }

        unsigned int pw[8];
        #pragma unroll
        for (int nt = 0; nt < 4; ++nt) {
            unsigned int w0, w1;
            asm("v_cvt_pk_bf16_f32 %0, %1, %2" : "=v"(w0) : "v"(sacc[nt][0]), "v"(sacc[nt][1]));
            asm("v_cvt_pk_bf16_f32 %0, %1, %2" : "=v"(w1) : "v"(sacc[nt][2]), "v"(sacc[nt][3]));
            pw[2 * nt] = w0;
            pw[2 * nt + 1] = w1;
        }

        #pragma unroll
        for (int ks = 0; ks < 2; ++ks) {
            unsigned int a0 = __shfl(pw[4 * ks + 0], srcA);
            unsigned int a1 = __shfl(pw[4 * ks + 1], srcA);
            unsigned int a2 = __shfl(pw[4 * ks + 0], srcB);
            unsigned int a3 = __shfl(pw[4 * ks + 1], srcB);
            unsigned int b0 = __shfl(pw[4 * ks + 2], srcA);
            unsigned int b1 = __shfl(pw[4 * ks + 3], srcA);
            unsigned int b2 = __shfl(pw[4 * ks + 2], srcB);
            unsigned int b3 = __shfl(pw[4 * ks + 3], srcB);
            unsigned int wparr[4] = {hi ? b0 : a0, hi ? b1 : a1, hi ? b2 : a2, hi ? b3 : a3};
            bf16x8 pa = *reinterpret_cast<bf16x8*>(wparr);
            #pragma unroll
            for (int dt = 0; dt < 8; ++dt) {
                bf16x8 vfr = *reinterpret_cast<const bf16x8*>(
                    vl + (dt * 16 + c) * 128 + ((ks * 64 + g * 16) ^ z));
                o_acc[dt] = __builtin_amdgcn_mfma_f32_16x16x32_bf16(vfr, pa, o_acc[dt], 0, 0, 0);
            }
        }
    };

    int selidx = 0, winidx = 0;
    while (mm) {
        int b = __builtin_ctz(mm);
        mm &= mm - 1;
        stage(b);
        __syncthreads();
        bool act;
        if (is_sel) {
            bool sb = (sm_wave >> b) & 1u;
            act = sb && ((selidx & 1) == w);
            selidx += sb ? 1 : 0;
        } else {
            bool wb = (b * 64 + 575 > tp);
            act = wb && ((winidx & 1) == w);
            winidx += wb ? 1 : 0;
        }
        if (act) compute(b);
        __syncthreads();
    }

    // ---- merge ----
    float* mrgf = smemf;
    if (w == 1) {
        if (g == 0) { mlbuf[wv][c][0] = m_run; mlbuf[wv][c][1] = l_run; }
        float* dst = mrgf + (wv >> 1) * (16 * 132) + c * 132;
        #pragma unroll
        for (int dt = 0; dt < 8; ++dt)
            *reinterpret_cast<float4*>(dst + dt * 16 + g * 4) =
                (float4){o_acc[dt][0], o_acc[dt][1], o_acc[dt][2], o_acc[dt][3]};
    }
    __syncthreads();
    if (w == 0) {
        float m1 = mlbuf[wv + 1][c][0];
        float l1 = mlbuf[wv + 1][c][1];
        float mn = fmaxf(m_run, m1);
        float a0 = exp2f(m_run - mn), a1 = exp2f(m1 - mn);
        l_run = a0 * l_run + a1 * l1;
        float inv = 1.f / l_run;
        const float* src = mrgf + (wv >> 1) * (16 * 132) + c * 132;
        #pragma unroll
        for (int dt = 0; dt < 8; ++dt) {
            float4 o1 = *reinterpret_cast<const float4*>(src + dt * 16 + g * 4);
            o_acc[dt][0] = (a0 * o_acc[dt][0] + a1 * o1.x) * inv;
            o_acc[dt][1] = (a0 * o_acc[dt][1] + a1 * o1.y) * inv;
            o_acc[dt][2] = (a0 * o_acc[dt][2] + a1 * o1.z) * inv;
            o_acc[dt][3] = (a0 * o_acc[dt][3] + a1 * o1.w) * inv;
        }
    }
    if (wv == 2) {
        float* dst = mrgf + (16 * 132) + c * 132;
        #pragma unroll
        for (int dt = 0; dt < 8; ++dt)
            *reinterpret_cast<float4*>(dst + dt * 16 + g * 4) =
                (float4){o_acc[dt][0], o_acc[dt][1], o_acc[dt][2], o_acc[dt][3]};
    }
    __syncthreads();
    if (wv != 0) return;

    // ---- fusion epilogue ----
    const float* owp = mrgf + (16 * 132) + c * 132;
    float4 oc[8], ow[8];
    #pragma unroll
    for (int dt = 0; dt < 8; ++dt) {
        int d = dt * 16 + g * 4;
        oc[dt] = (float4){bf2f(ocmp[c * 136 + d]), bf2f(ocmp[c * 136 + d + 1]),
                          bf2f(ocmp[c * 136 + d + 2]), bf2f(ocmp[c * 136 + d + 3])};
        ow[dt] = *reinterpret_cast<const float4*>(owp + dt * 16 + g * 4);
    }
    const float* fwp = fw + hh * 3 * 384;
    float p0 = 0.f, p1 = 0.f, p2 = 0.f;
    #pragma unroll
    for (int dt = 0; dt < 8; ++dt) {
        #pragma unroll
        for (int i = 0; i < 4; ++i) {
            int d = dt * 16 + g * 4 + i;
            float a = (i == 0) ? oc[dt].x : (i == 1) ? oc[dt].y : (i == 2) ? oc[dt].z : oc[dt].w;
            float bsl = o_acc[dt][i];
            float cw = (i == 0) ? ow[dt].x : (i == 1) ? ow[dt].y : (i == 2) ? ow[dt].z : ow[dt].w;
            p0 += fwp[0 * 384 + d] * a + fwp[0 * 384 + 128 + d] * bsl + fwp[0 * 384 + 256 + d] * cw;
            p1 += fwp[1 * 384 + d] * a + fwp[1 * 384 + 128 + d] * bsl + fwp[1 * 384 + 256 + d] * cw;
            p2 += fwp[2 * 384 + d] * a + fwp[2 * 384 + 128 + d] * bsl + fwp[2 * 384 + 256 + d] * cw;
        }
    }
    p0 += __shfl_xor(p0, 16); p0 += __shfl_xor(p0, 32);
    p1 += __shfl_xor(p1, 16); p1 += __shfl_xor(p1, 32);
    p2 += __shfl_xor(p2, 16); p2 += __shfl_xor(p2, 32);
    float mx = fmaxf(p0, fmaxf(p1, p2));
    float e0 = expf(p0 - mx), e1 = expf(p1 - mx), e2 = expf(p2 - mx);
    float inv3 = 1.f / (e0 + e1 + e2);
    float w0 = e0 * inv3, w1 = e1 * inv3, w2 = e2 * inv3;
    #pragma unroll
    for (int dt = 0; dt < 8; ++dt) {
        float4 r;
        r.x = w0 * oc[dt].x + w1 * o_acc[dt][0] + w2 * ow[dt].x;
        r.y = w0 * oc[dt].y + w1 * o_acc[dt][1] + w2 * ow[dt].y;
        r.z = w0 * oc[dt].z + w1 * o_acc[dt][2] + w2 * ow[dt].z;
        r.w = w0 * oc[dt].w + w1 * o_acc[dt][3] + w2 * ow[dt].w;
        *reinterpret_cast<float4*>(out + th * 1024 + hh * 128 + dt * 16 + g * 4) = r;
    }
}

extern "C" void kernel_launch(void* const* d_in, const int* in_sizes, int n_in,
                              void* d_out, int out_size, void* d_ws, size_t ws_size,
                              hipStream_t stream) {
    (void)in_sizes; (void)n_in; (void)out_size; (void)ws_size;
    const float* q   = (const float*)d_in[0];
    const float* k   = (const float*)d_in[1];
    const float* v   = (const float*)d_in[2];
    const float* wk  = (const float*)d_in[3];
    const float* wvg = (const float*)d_in[4];
    const float* fw  = (const float*)d_in[5];
    float* out = (float*)d_out;
    float* ws = (float*)d_ws;
    float* ck = ws;
    float* cv = ws + NCMP * 128;
    unsigned short* kswz = (unsigned short*)(ws + 2 * NCMP * 128 + 2048);
    unsigned short* vswz = kswz + 2048 * 128;

    k_prep<<<dim3(64 + 2 * NCMP), dim3(256), 0, stream>>>(k, v, wk, wvg, ck, cv, kswz, vswz);
    k_main<<<dim3(1024), dim3(256), 0, stream>>>(q, ck, cv, kswz, vswz, fw, out);
}

// Round 19
// 136.542 us; speedup vs baseline: 1.3677x; 1.3677x over previous
//
#include <hip/hip_runtime.h>

// NSA constants
#define NCMP 127
#define SCALE 0.08838834764831845f
#define QSCALE (0.08838834764831845f * 1.4426950408889634f)  // SCALE * log2(e)

typedef __attribute__((ext_vector_type(8))) short bf16x8;
typedef __attribute__((ext_vector_type(4))) float f32x4;

__device__ __forceinline__ unsigned short f2bf(float x) {
    union { float f; unsigned u; } a; a.f = x;
    unsigned r = a.u + 0x7fffu + ((a.u >> 16) & 1u);
    return (unsigned short)(r >> 16);
}
__device__ __forceinline__ float bf2f(unsigned short s) {
    union { unsigned u; float f; } x; x.u = ((unsigned)s) << 16; return x.f;
}
__device__ __forceinline__ float dot4(float4 a, float4 b) {
    return a.x * b.x + a.y * b.y + a.z * b.z + a.w * b.w;
}
__device__ __forceinline__ void gload_lds16(const void* g, void* l) {
    __builtin_amdgcn_global_load_lds(
        (const __attribute__((address_space(1))) unsigned int*)g,
        (__attribute__((address_space(3))) unsigned int*)l, 16, 0, 0);
}

// ---- Kernel P: fused prep — convert (bid<64) + compress (bid>=64) ----
__global__ __launch_bounds__(256) void k_prep(const float* __restrict__ k,
                                              const float* __restrict__ v,
                                              const float* __restrict__ wk,
                                              const float* __restrict__ wv,
                                              float* __restrict__ ck,
                                              float* __restrict__ cv,
                                              unsigned short* __restrict__ kswz,
                                              unsigned short* __restrict__ vswz) {
    __shared__ float shbuf[4128];
    int tid = threadIdx.x;

    if (blockIdx.x < 64) {
        // ================= convert =================
        unsigned short* vl = (unsigned short*)shbuf;   // [32][132]
        int wgid = blockIdx.x;
        int b = wgid >> 1, half = wgid & 1;
        int r0 = b * 64 + half * 32;

        #pragma unroll
        for (int it = 0; it < 4; ++it) {
            int idx = it * 1024 + tid * 4;
            int row = r0 + (idx >> 7), d = idx & 127;
            float4 x = *reinterpret_cast<const float4*>(k + r0 * 128 + idx);
            unsigned short o[4] = {f2bf(x.x), f2bf(x.y), f2bf(x.z), f2bf(x.w)};
            char* dst = (char*)kswz + row * 256 + ((d * 2) ^ ((row & 7) << 4));
            *reinterpret_cast<unsigned long long*>(dst) = *reinterpret_cast<unsigned long long*>(o);
        }
        #pragma unroll
        for (int it = 0; it < 4; ++it) {
            int idx = it * 1024 + tid * 4;
            int pl = idx >> 7, d = idx & 127;
            float4 x = *reinterpret_cast<const float4*>(v + r0 * 128 + idx);
            unsigned short o[4] = {f2bf(x.x), f2bf(x.y), f2bf(x.z), f2bf(x.w)};
            *reinterpret_cast<unsigned long long*>(&vl[pl * 132 + d]) =
                *reinterpret_cast<unsigned long long*>(o);
        }
        __syncthreads();
        #pragma unroll
        for (int it = 0; it < 2; ++it) {
            int task = it * 256 + tid;
            int d = task >> 2, cjs = task & 3;
            int src_chunk = half * 4 + cjs;
            int dst_chunk = src_chunk ^ (d & 7);
            union { unsigned short s[8]; uint4 q; } u;
            #pragma unroll
            for (int i = 0; i < 8; ++i) u.s[i] = vl[(cjs * 8 + i) * 132 + d];
            char* dst = (char*)vswz + b * 16384 + d * 128 + dst_chunk * 16;
            *reinterpret_cast<uint4*>(dst) = u.q;
        }
    } else {
        // ================= compress =================
        float* blk = shbuf;
        float* gate = shbuf + 4096;
        int id = blockIdx.x - 64;
        int n = id >> 1;
        int which = id & 1;
        const float* src = which ? v : k;
        const float* w   = which ? wv : wk;
        float* out       = which ? cv : ck;

        {
            const float4* sp = reinterpret_cast<const float4*>(src + n * 16 * 128);
            float4* bp = reinterpret_cast<float4*>(blk);
            #pragma unroll
            for (int i = 0; i < 4; ++i) bp[tid + 256 * i] = sp[tid + 256 * i];
        }
        __syncthreads();
        {
            int j = tid >> 3, sub = tid & 7;
            const float4* wp = reinterpret_cast<const float4*>(w + j * 4096);
            const float4* bp = reinterpret_cast<const float4*>(blk);
            float s0 = 0.f, s1 = 0.f, s2 = 0.f, s3 = 0.f;
            for (int i = sub * 4; i < 1024; i += 32) {
                float4 w0 = wp[i], w1 = wp[i + 1], w2 = wp[i + 2], w3 = wp[i + 3];
                s0 += dot4(bp[i], w0);
                s1 += dot4(bp[i + 1], w1);
                s2 += dot4(bp[i + 2], w2);
                s3 += dot4(bp[i + 3], w3);
            }
            float s = (s0 + s1) + (s2 + s3);
            s += __shfl_xor(s, 1);
            s += __shfl_xor(s, 2);
            s += __shfl_xor(s, 4);
            if (sub == 0) gate[j] = s;
        }
        __syncthreads();
        if (tid < 32) {
            float gv = gate[tid];
            float m = gv;
            #pragma unroll
            for (int off = 16; off > 0; off >>= 1) m = fmaxf(m, __shfl_xor(m, off));
            float e = expf(gv - m);
            float ss = e;
            #pragma unroll
            for (int off = 16; off > 0; off >>= 1) ss += __shfl_xor(ss, off);
            gate[tid] = e / ss;
        }
        __syncthreads();
        if (tid < 128) {
            float acc = 0.f;
            #pragma unroll
            for (int kx = 0; kx < 32; ++kx) acc += gate[kx] * blk[kx * 128 + tid];
            out[n * 128 + tid] = acc;
        }
    }
}

// -------- Kernel C: fully-fused NSA per t-pair --------
__global__ __launch_bounds__(256, 4) void k_main(const float* __restrict__ q,
                                              const float* __restrict__ ck,
                                              const float* __restrict__ cv,
                                              const unsigned short* __restrict__ kswz,
                                              const unsigned short* __restrict__ vswz,
                                              const float* __restrict__ fw,
                                              float* __restrict__ out) {
    __shared__ float smemf[8192];             // 32KB: phase0 sc/pg/adj, tile, mrg
    __shared__ unsigned short ocmp[16 * 136];
    __shared__ unsigned int selm[2];
    __shared__ float mlbuf[4][16][2];
    char* smem = (char*)smemf;

    int bid = blockIdx.x;
    int pairidx = (bid < 512) ? (1023 - bid) : (bid - 512);
    int tp = pairidx * 2;

    int tid = threadIdx.x;
    int wv = tid >> 6, ln = tid & 63;
    int c = ln & 15, g = ln >> 4;
    bool is_sel = (wv < 2);
    int w = wv & 1;

    int th = tp + (c >> 3);
    int hh = c & 7;

    // Q fragments for the block loop
    bf16x8 qf[4];
    {
        const float* qp = q + th * 1024 + hh * 128;
        #pragma unroll
        for (int ks = 0; ks < 4; ++ks) {
            int d0 = ks * 32 + g * 8;
            float4 x = *reinterpret_cast<const float4*>(qp + d0);
            float4 y = *reinterpret_cast<const float4*>(qp + d0 + 4);
            bf16x8 f;
            f[0]=(short)f2bf(x.x*QSCALE); f[1]=(short)f2bf(x.y*QSCALE); f[2]=(short)f2bf(x.z*QSCALE); f[3]=(short)f2bf(x.w*QSCALE);
            f[4]=(short)f2bf(y.x*QSCALE); f[5]=(short)f2bf(y.y*QSCALE); f[6]=(short)f2bf(y.z*QSCALE); f[7]=(short)f2bf(y.w*QSCALE);
            qf[ks] = f;
        }
    }

    // ======== phase 0: compressed branch + top-k select ========
    float* sc   = smemf;                   // [16][132] f32
    float* pgb  = smemf + 16 * 132;        // [2][128]
    float* adjb = smemf + 16 * 132 + 256;  // [2][32]

    // 0a: scores — wave owns 4 rows; each ck 64B load feeds 4 rows; 8 n's/pass
    {
        int ds = ln & 7, ng = ln >> 3;     // 8 lanes per n, 8 n's per pass
        int d0 = ds * 16;
        float4 qr[4][4];
        #pragma unroll
        for (int rr = 0; rr < 4; ++rr) {
            int row = wv * 4 + rr;
            const float4* qp = reinterpret_cast<const float4*>(
                q + (tp + (row >> 3)) * 1024 + (row & 7) * 128 + d0);
            #pragma unroll
            for (int cc = 0; cc < 4; ++cc) qr[rr][cc] = qp[cc];
        }
        #pragma unroll 2
        for (int pass = 0; pass < 16; ++pass) {
            int n = pass * 8 + ng;
            if (n >= NCMP) continue;
            const float4* kp = reinterpret_cast<const float4*>(ck + n * 128 + d0);
            float4 k0 = kp[0], k1 = kp[1], k2 = kp[2], k3 = kp[3];
            float part[4];
            #pragma unroll
            for (int rr = 0; rr < 4; ++rr)
                part[rr] = dot4(qr[rr][0], k0) + dot4(qr[rr][1], k1) +
                           dot4(qr[rr][2], k2) + dot4(qr[rr][3], k3);
            #pragma unroll
            for (int off = 1; off < 8; off <<= 1)
                #pragma unroll
                for (int rr = 0; rr < 4; ++rr) part[rr] += __shfl_xor(part[rr], off);
            if (ds == 0) {
                #pragma unroll
                for (int rr = 0; rr < 4; ++rr)
                    sc[(wv * 4 + rr) * 132 + n] = part[rr] * SCALE;
            }
        }
    }
    __syncthreads();
    // 0b: masked softmax per row (16 lanes/row)
    {
        int r = tid >> 4, nl = tid & 15;
        int t = tp + (r >> 3);
        int nvalid = (t >= 31) ? (((t - 31) >> 4) + 1) : 0;
        if (nvalid > NCMP) nvalid = NCMP;
        float* row = sc + r * 132;
        float m = -3e38f;
        for (int n = nl; n < nvalid; n += 16) m = fmaxf(m, row[n]);
        m = fmaxf(m, __shfl_xor(m, 1));
        m = fmaxf(m, __shfl_xor(m, 2));
        m = fmaxf(m, __shfl_xor(m, 4));
        m = fmaxf(m, __shfl_xor(m, 8));
        float ss = 0.f;
        for (int n = nl; n < 128; n += 16) {
            float e = (n < nvalid) ? expf(row[n] - m) : 0.f;
            ss += e;
            row[n] = e;
        }
        ss += __shfl_xor(ss, 1);
        ss += __shfl_xor(ss, 2);
        ss += __shfl_xor(ss, 4);
        ss += __shfl_xor(ss, 8);
        float inv = (ss > 0.f) ? 1.f / ss : 0.f;
        for (int n = nl; n < 128; n += 16) row[n] *= inv;
    }
    __syncthreads();
    // 0c: head-sum pg
    {
        int tl = tid >> 7, n = tid & 127;
        if (n < NCMP) {
            float s = 0.f;
            #pragma unroll
            for (int h = 0; h < 8; ++h) s += sc[(tl * 8 + h) * 132 + n];
            pgb[tl * 128 + n] = s;
        }
    }
    __syncthreads();
    // 0d: select-block scores + causal/forced adjust
    if (tid < 64) {
        int tl = tid >> 5, s32 = tid & 31;
        float s = 0.f;
        #pragma unroll
        for (int j = 0; j < 4; ++j) {
            int n = s32 * 4 + j;
            if (n < NCMP) s += pgb[tl * 128 + n];
        }
        int qblk = (tp + tl) >> 6;
        adjb[tl * 32 + s32] = (s32 > qblk) ? -1e30f
                            : s + ((s32 == 0 || s32 > qblk - 2) ? 1e30f : 0.f);
    }
    __syncthreads();
    // 0e: wave0 top-16; all waves compute o_cmp (cv load shared across 4 rows)
    if (wv == 0) {
        int grp = ln >> 5, s32 = ln & 31;
        float val = adjb[grp * 32 + s32];
        unsigned int msk = 0u;
        for (int it = 0; it < 16; ++it) {
            float bv = val; int bi = s32;
            #pragma unroll
            for (int off = 1; off < 32; off <<= 1) {
                float ov = __shfl_xor(bv, off);
                int oi = __shfl_xor(bi, off);
                if (ov > bv || (ov == bv && oi < bi)) { bv = ov; bi = oi; }
            }
            if (bv <= -5e29f) break;
            msk |= 1u << bi;
            if (s32 == bi) val = -2e38f;
        }
        if (s32 == 0) selm[grp] = msk;
    }
    {
        int d = ln * 2;
        int t = tp + (wv >> 1);            // rows wv*4..wv*4+3 share the same t
        int nv = (t >= 31) ? (((t - 31) >> 4) + 1) : 0;
        if (nv > NCMP) nv = NCMP;
        float a0[4] = {0.f, 0.f, 0.f, 0.f};
        float a1[4] = {0.f, 0.f, 0.f, 0.f};
        const float* scb = sc + (wv * 4) * 132;
        for (int n = 0; n < nv; ++n) {
            float2 vvv = *reinterpret_cast<const float2*>(cv + n * 128 + d);
            #pragma unroll
            for (int rr = 0; rr < 4; ++rr) {
                float p = scb[rr * 132 + n];
                a0[rr] += p * vvv.x;
                a1[rr] += p * vvv.y;
            }
        }
        #pragma unroll
        for (int rr = 0; rr < 4; ++rr) {
            unsigned int wrd = (unsigned int)f2bf(a0[rr]) | ((unsigned int)f2bf(a1[rr]) << 16);
            *reinterpret_cast<unsigned int*>(&ocmp[(wv * 4 + rr) * 136 + d]) = wrd;
        }
    }
    __syncthreads();
    unsigned int sm0 = selm[0], sm1 = selm[1];

    // ======== block loop (identical to R13-R15) ========
    unsigned int sm_wave = sm0 | sm1;
    unsigned int smc = (c >> 3) ? sm1 : sm0;

    float m_run = -1e30f, l_run = 0.f;
    f32x4 o_acc[8];
    #pragma unroll
    for (int dt = 0; dt < 8; ++dt) o_acc[dt] = (f32x4){0.f, 0.f, 0.f, 0.f};

    int qblk_max = (tp + 1) >> 6;
    int wlo = (tp >= 575) ? (((tp - 575) >> 6) + 1) : 0;
    unsigned int all = (qblk_max >= 31) ? 0xFFFFFFFFu : ((1u << (qblk_max + 1)) - 1u);
    unsigned int wmask = all & ~((1u << wlo) - 1u);
    unsigned int mm = (sm_wave & all) | wmask;

    int srcA = ((g & 1) << 5) + c;
    int srcB = srcA + 16;
    bool hi = (g >= 2);

    auto stage = [&](int b) {
        const char* ks = (const char*)kswz + b * 16384;
        const char* vs = (const char*)vswz + b * 16384;
        char* kd = smem;
        char* vd = smem + 16384;
        int lo = wv * 1024;
        int so = lo + ln * 16;
        #pragma unroll
        for (int j = 0; j < 4; ++j) {
            gload_lds16(ks + j * 4096 + so, kd + j * 4096 + lo);
            gload_lds16(vs + j * 4096 + so, vd + j * 4096 + lo);
        }
    };

    auto compute = [&](int b) {
        const char* kl = smem;
        const char* vl = smem + 16384;
        int z = (c & 7) << 4;

        f32x4 sacc[4];
        #pragma unroll
        for (int nt = 0; nt < 4; ++nt) {
            f32x4 acc = (f32x4){0.f, 0.f, 0.f, 0.f};
            #pragma unroll
            for (int ks = 0; ks < 4; ++ks) {
                bf16x8 kf = *reinterpret_cast<const bf16x8*>(
                    kl + (nt * 16 + c) * 256 + ((ks * 64 + g * 16) ^ z));
                acc = __builtin_amdgcn_mfma_f32_16x16x32_bf16(kf, qf[ks], acc, 0, 0, 0);
            }
            sacc[nt] = acc;
        }

        bool selbit = (smc >> b) & 1u;
        float mloc = -1e30f;
        #pragma unroll
        for (int nt = 0; nt < 4; ++nt) {
            #pragma unroll
            for (int i = 0; i < 4; ++i) {
                int pos = b * 64 + nt * 16 + g * 4 + i;
                bool val;
                if (is_sel) val = selbit && (pos <= th);
                else        val = (pos <= th) && (pos + 512 > th);
                float s = val ? sacc[nt][i] : -1e30f;
                sacc[nt][i] = s;
                mloc = fmaxf(mloc, s);
            }
        }
        mloc = fmaxf(mloc, __shfl_xor(mloc, 16));
        mloc = fmaxf(mloc, __shfl_xor(mloc, 32));
        float mn = fmaxf(m_run, mloc);
        float al = exp2f(m_run - mn);

        float lsum = 0.f;
        #pragma unroll
        for (int nt = 0; nt < 4; ++nt) {
            #pragma unroll
            for (int i = 0; i < 4; ++i) {
                float s = sacc[nt][i];
                float p = (s > -5e29f) ? exp2f(s - mn) : 0.f;
                sacc[nt][i] = p;
                lsum += p;
            }
        }
        lsum += __shfl_xor(lsum, 16);
        lsum += __shfl_xor(lsum, 32);
        m_run = mn;
        l_run = l_run * al + lsum;

        if (__any(al != 1.f)) {
            #pragma unroll
            for (int dt = 0; dt < 8; ++dt)
                #pragma unroll
                for (int i = 0; i < 4; ++i)
                    o_acc[dt][i] *= al;
        }

        unsigned int pw[8];
        #pragma unroll
        for (int nt = 0; nt < 4; ++nt) {
            unsigned int w0, w1;
            asm("v_cvt_pk_bf16_f32 %0, %1, %2" : "=v"(w0) : "v"(sacc[nt][0]), "v"(sacc[nt][1]));
            asm("v_cvt_pk_bf16_f32 %0, %1, %2" : "=v"(w1) : "v"(sacc[nt][2]), "v"(sacc[nt][3]));
            pw[2 * nt] = w0;
            pw[2 * nt + 1] = w1;
        }

        #pragma unroll
        for (int ks = 0; ks < 2; ++ks) {
            unsigned int a0 = __shfl(pw[4 * ks + 0], srcA);
            unsigned int a1 = __shfl(pw[4 * ks + 1], srcA);
            unsigned int a2 = __shfl(pw[4 * ks + 0], srcB);
            unsigned int a3 = __shfl(pw[4 * ks + 1], srcB);
            unsigned int b0 = __shfl(pw[4 * ks + 2], srcA);
            unsigned int b1 = __shfl(pw[4 * ks + 3], srcA);
            unsigned int b2 = __shfl(pw[4 * ks + 2], srcB);
            unsigned int b3 = __shfl(pw[4 * ks + 3], srcB);
            unsigned int wparr[4] = {hi ? b0 : a0, hi ? b1 : a1, hi ? b2 : a2, hi ? b3 : a3};
            bf16x8 pa = *reinterpret_cast<bf16x8*>(wparr);
            #pragma unroll
            for (int dt = 0; dt < 8; ++dt) {
                bf16x8 vfr = *reinterpret_cast<const bf16x8*>(
                    vl + (dt * 16 + c) * 128 + ((ks * 64 + g * 16) ^ z));
                o_acc[dt] = __builtin_amdgcn_mfma_f32_16x16x32_bf16(vfr, pa, o_acc[dt], 0, 0, 0);
            }
        }
    };

    int selidx = 0, winidx = 0;
    while (mm) {
        int b = __builtin_ctz(mm);
        mm &= mm - 1;
        stage(b);
        __syncthreads();
        bool act;
        if (is_sel) {
            bool sb = (sm_wave >> b) & 1u;
            act = sb && ((selidx & 1) == w);
            selidx += sb ? 1 : 0;
        } else {
            bool wb = (b * 64 + 575 > tp);
            act = wb && ((winidx & 1) == w);
            winidx += wb ? 1 : 0;
        }
        if (act) compute(b);
        __syncthreads();
    }

    // ---- merge ----
    float* mrgf = smemf;
    if (w == 1) {
        if (g == 0) { mlbuf[wv][c][0] = m_run; mlbuf[wv][c][1] = l_run; }
        float* dst = mrgf + (wv >> 1) * (16 * 132) + c * 132;
        #pragma unroll
        for (int dt = 0; dt < 8; ++dt)
            *reinterpret_cast<float4*>(dst + dt * 16 + g * 4) =
                (float4){o_acc[dt][0], o_acc[dt][1], o_acc[dt][2], o_acc[dt][3]};
    }
    __syncthreads();
    if (w == 0) {
        float m1 = mlbuf[wv + 1][c][0];
        float l1 = mlbuf[wv + 1][c][1];
        float mn = fmaxf(m_run, m1);
        float a0 = exp2f(m_run - mn), a1 = exp2f(m1 - mn);
        l_run = a0 * l_run + a1 * l1;
        float inv = 1.f / l_run;
        const float* src = mrgf + (wv >> 1) * (16 * 132) + c * 132;
        #pragma unroll
        for (int dt = 0; dt < 8; ++dt) {
            float4 o1 = *reinterpret_cast<const float4*>(src + dt * 16 + g * 4);
            o_acc[dt][0] = (a0 * o_acc[dt][0] + a1 * o1.x) * inv;
            o_acc[dt][1] = (a0 * o_acc[dt][1] + a1 * o1.y) * inv;
            o_acc[dt][2] = (a0 * o_acc[dt][2] + a1 * o1.z) * inv;
            o_acc[dt][3] = (a0 * o_acc[dt][3] + a1 * o1.w) * inv;
        }
    }
    if (wv == 2) {
        float* dst = mrgf + (16 * 132) + c * 132;
        #pragma unroll
        for (int dt = 0; dt < 8; ++dt)
            *reinterpret_cast<float4*>(dst + dt * 16 + g * 4) =
                (float4){o_acc[dt][0], o_acc[dt][1], o_acc[dt][2], o_acc[dt][3]};
    }
    __syncthreads();
    if (wv != 0) return;

    // ---- fusion epilogue ----
    const float* owp = mrgf + (16 * 132) + c * 132;
    float4 oc[8], ow[8];
    #pragma unroll
    for (int dt = 0; dt < 8; ++dt) {
        int d = dt * 16 + g * 4;
        oc[dt] = (float4){bf2f(ocmp[c * 136 + d]), bf2f(ocmp[c * 136 + d + 1]),
                          bf2f(ocmp[c * 136 + d + 2]), bf2f(ocmp[c * 136 + d + 3])};
        ow[dt] = *reinterpret_cast<const float4*>(owp + dt * 16 + g * 4);
    }
    const float* fwp = fw + hh * 3 * 384;
    float p0 = 0.f, p1 = 0.f, p2 = 0.f;
    #pragma unroll
    for (int dt = 0; dt < 8; ++dt) {
        #pragma unroll
        for (int i = 0; i < 4; ++i) {
            int d = dt * 16 + g * 4 + i;
            float a = (i == 0) ? oc[dt].x : (i == 1) ? oc[dt].y : (i == 2) ? oc[dt].z : oc[dt].w;
            float bsl = o_acc[dt][i];
            float cw = (i == 0) ? ow[dt].x : (i == 1) ? ow[dt].y : (i == 2) ? ow[dt].z : ow[dt].w;
            p0 += fwp[0 * 384 + d] * a + fwp[0 * 384 + 128 + d] * bsl + fwp[0 * 384 + 256 + d] * cw;
            p1 += fwp[1 * 384 + d] * a + fwp[1 * 384 + 128 + d] * bsl + fwp[1 * 384 + 256 + d] * cw;
            p2 += fwp[2 * 384 + d] * a + fwp[2 * 384 + 128 + d] * bsl + fwp[2 * 384 + 256 + d] * cw;
        }
    }
    p0 += __shfl_xor(p0, 16); p0 += __shfl_xor(p0, 32);
    p1 += __shfl_xor(p1, 16); p1 += __shfl_xor(p1, 32);
    p2 += __shfl_xor(p2, 16); p2 += __shfl_xor(p2, 32);
    float mx = fmaxf(p0, fmaxf(p1, p2));
    float e0 = expf(p0 - mx), e1 = expf(p1 - mx), e2 = expf(p2 - mx);
    float inv3 = 1.f / (e0 + e1 + e2);
    float w0 = e0 * inv3, w1 = e1 * inv3, w2 = e2 * inv3;
    #pragma unroll
    for (int dt = 0; dt < 8; ++dt) {
        float4 r;
        r.x = w0 * oc[dt].x + w1 * o_acc[dt][0] + w2 * ow[dt].x;
        r.y = w0 * oc[dt].y + w1 * o_acc[dt][1] + w2 * ow[dt].y;
        r.z = w0 * oc[dt].z + w1 * o_acc[dt][2] + w2 * ow[dt].z;
        r.w = w0 * oc[dt].w + w1 * o_acc[dt][3] + w2 * ow[dt].w;
        *reinterpret_cast<float4*>(out + th * 1024 + hh * 128 + dt * 16 + g * 4) = r;
    }
}

extern "C" void kernel_launch(void* const* d_in, const int* in_sizes, int n_in,
                              void* d_out, int out_size, void* d_ws, size_t ws_size,
                              hipStream_t stream) {
    (void)in_sizes; (void)n_in; (void)out_size; (void)ws_size;
    const float* q   = (const float*)d_in[0];
    const float* k   = (const float*)d_in[1];
    const float* v   = (const float*)d_in[2];
    const float* wk  = (const float*)d_in[3];
    const float* wvg = (const float*)d_in[4];
    const float* fw  = (const float*)d_in[5];
    float* out = (float*)d_out;
    float* ws = (float*)d_ws;
    float* ck = ws;
    float* cv = ws + NCMP * 128;
    unsigned short* kswz = (unsigned short*)(ws + 2 * NCMP * 128 + 2048);
    unsigned short* vswz = kswz + 2048 * 128;

    k_prep<<<dim3(64 + 2 * NCMP), dim3(256), 0, stream>>>(k, v, wk, wvg, ck, cv, kswz, vswz);
    k_main<<<dim3(1024), dim3(256), 0, stream>>>(q, ck, cv, kswz, vswz, fw, out);
}

// Round 20
// 114.964 us; speedup vs baseline: 1.6244x; 1.1877x over previous
//
#include <hip/hip_runtime.h>

// NSA constants
#define NCMP 127
#define SCALE 0.08838834764831845f
#define QSCALE (0.08838834764831845f * 1.4426950408889634f)  // SCALE * log2(e)

typedef __attribute__((ext_vector_type(8))) short bf16x8;
typedef __attribute__((ext_vector_type(4))) float f32x4;

__device__ __forceinline__ unsigned short f2bf(float x) {
    union { float f; unsigned u; } a; a.f = x;
    unsigned r = a.u + 0x7fffu + ((a.u >> 16) & 1u);
    return (unsigned short)(r >> 16);
}
__device__ __forceinline__ float bf2f(unsigned short s) {
    union { unsigned u; float f; } x; x.u = ((unsigned)s) << 16; return x.f;
}
__device__ __forceinline__ float dot4(float4 a, float4 b) {
    return a.x * b.x + a.y * b.y + a.z * b.z + a.w * b.w;
}
__device__ __forceinline__ void gload_lds16(const void* g, void* l) {
    __builtin_amdgcn_global_load_lds(
        (const __attribute__((address_space(1))) unsigned int*)g,
        (__attribute__((address_space(3))) unsigned int*)l, 16, 0, 0);
}

// ---- Kernel P: fused prep — convert (bid<64) + compress (bid>=64) ----
__global__ __launch_bounds__(256) void k_prep(const float* __restrict__ k,
                                              const float* __restrict__ v,
                                              const float* __restrict__ wk,
                                              const float* __restrict__ wv,
                                              float* __restrict__ ck,
                                              float* __restrict__ cv,
                                              unsigned short* __restrict__ kswz,
                                              unsigned short* __restrict__ vswz) {
    __shared__ float shbuf[4128];
    int tid = threadIdx.x;

    if (blockIdx.x < 64) {
        // ================= convert =================
        unsigned short* vl = (unsigned short*)shbuf;   // [32][132]
        int wgid = blockIdx.x;
        int b = wgid >> 1, half = wgid & 1;
        int r0 = b * 64 + half * 32;

        #pragma unroll
        for (int it = 0; it < 4; ++it) {
            int idx = it * 1024 + tid * 4;
            int row = r0 + (idx >> 7), d = idx & 127;
            float4 x = *reinterpret_cast<const float4*>(k + r0 * 128 + idx);
            unsigned short o[4] = {f2bf(x.x), f2bf(x.y), f2bf(x.z), f2bf(x.w)};
            char* dst = (char*)kswz + row * 256 + ((d * 2) ^ ((row & 7) << 4));
            *reinterpret_cast<unsigned long long*>(dst) = *reinterpret_cast<unsigned long long*>(o);
        }
        #pragma unroll
        for (int it = 0; it < 4; ++it) {
            int idx = it * 1024 + tid * 4;
            int pl = idx >> 7, d = idx & 127;
            float4 x = *reinterpret_cast<const float4*>(v + r0 * 128 + idx);
            unsigned short o[4] = {f2bf(x.x), f2bf(x.y), f2bf(x.z), f2bf(x.w)};
            *reinterpret_cast<unsigned long long*>(&vl[pl * 132 + d]) =
                *reinterpret_cast<unsigned long long*>(o);
        }
        __syncthreads();
        #pragma unroll
        for (int it = 0; it < 2; ++it) {
            int task = it * 256 + tid;
            int d = task >> 2, cjs = task & 3;
            int src_chunk = half * 4 + cjs;
            int dst_chunk = src_chunk ^ (d & 7);
            union { unsigned short s[8]; uint4 q; } u;
            #pragma unroll
            for (int i = 0; i < 8; ++i) u.s[i] = vl[(cjs * 8 + i) * 132 + d];
            char* dst = (char*)vswz + b * 16384 + d * 128 + dst_chunk * 16;
            *reinterpret_cast<uint4*>(dst) = u.q;
        }
    } else {
        // ================= compress =================
        float* blk = shbuf;
        float* gate = shbuf + 4096;
        int id = blockIdx.x - 64;
        int n = id >> 1;
        int which = id & 1;
        const float* src = which ? v : k;
        const float* w   = which ? wv : wk;
        float* out       = which ? cv : ck;

        {
            const float4* sp = reinterpret_cast<const float4*>(src + n * 16 * 128);
            float4* bp = reinterpret_cast<float4*>(blk);
            #pragma unroll
            for (int i = 0; i < 4; ++i) bp[tid + 256 * i] = sp[tid + 256 * i];
        }
        __syncthreads();
        {
            int j = tid >> 3, sub = tid & 7;
            const float4* wp = reinterpret_cast<const float4*>(w + j * 4096);
            const float4* bp = reinterpret_cast<const float4*>(blk);
            float s0 = 0.f, s1 = 0.f, s2 = 0.f, s3 = 0.f;
            for (int i = sub * 4; i < 1024; i += 32) {
                float4 w0 = wp[i], w1 = wp[i + 1], w2 = wp[i + 2], w3 = wp[i + 3];
                s0 += dot4(bp[i], w0);
                s1 += dot4(bp[i + 1], w1);
                s2 += dot4(bp[i + 2], w2);
                s3 += dot4(bp[i + 3], w3);
            }
            float s = (s0 + s1) + (s2 + s3);
            s += __shfl_xor(s, 1);
            s += __shfl_xor(s, 2);
            s += __shfl_xor(s, 4);
            if (sub == 0) gate[j] = s;
        }
        __syncthreads();
        if (tid < 32) {
            float gv = gate[tid];
            float m = gv;
            #pragma unroll
            for (int off = 16; off > 0; off >>= 1) m = fmaxf(m, __shfl_xor(m, off));
            float e = expf(gv - m);
            float ss = e;
            #pragma unroll
            for (int off = 16; off > 0; off >>= 1) ss += __shfl_xor(ss, off);
            gate[tid] = e / ss;
        }
        __syncthreads();
        if (tid < 128) {
            float acc = 0.f;
            #pragma unroll
            for (int kx = 0; kx < 32; ++kx) acc += gate[kx] * blk[kx * 128 + tid];
            out[n * 128 + tid] = acc;
        }
    }
}

// -------- Kernel C: fully-fused NSA per t-pair; position-half split in block loop --------
// waves 0,1 = select (positions [0,32)/[32,64) of every sel block)
// waves 2,3 = window (same position split)
__global__ __launch_bounds__(256, 4) void k_main(const float* __restrict__ q,
                                              const float* __restrict__ ck,
                                              const float* __restrict__ cv,
                                              const unsigned short* __restrict__ kswz,
                                              const unsigned short* __restrict__ vswz,
                                              const float* __restrict__ fw,
                                              float* __restrict__ out) {
    __shared__ float smemf[8192];             // 32KB: phase0 sc/pg/adj, tile, mrg
    __shared__ unsigned short ocmp[16 * 136];
    __shared__ unsigned int selm[2];
    __shared__ float mlbuf[4][16][2];
    char* smem = (char*)smemf;

    int bid = blockIdx.x;
    int pairidx = (bid < 512) ? (1023 - bid) : (bid - 512);
    int tp = pairidx * 2;

    int tid = threadIdx.x;
    int wv = tid >> 6, ln = tid & 63;
    int c = ln & 15, g = ln >> 4;
    bool is_sel = (wv < 2);
    int w = wv & 1;                           // position half: w*32 .. w*32+31

    int th = tp + (c >> 3);
    int hh = c & 7;

    // Q fragments for the block loop
    bf16x8 qf[4];
    {
        const float* qp = q + th * 1024 + hh * 128;
        #pragma unroll
        for (int ks = 0; ks < 4; ++ks) {
            int d0 = ks * 32 + g * 8;
            float4 x = *reinterpret_cast<const float4*>(qp + d0);
            float4 y = *reinterpret_cast<const float4*>(qp + d0 + 4);
            bf16x8 f;
            f[0]=(short)f2bf(x.x*QSCALE); f[1]=(short)f2bf(x.y*QSCALE); f[2]=(short)f2bf(x.z*QSCALE); f[3]=(short)f2bf(x.w*QSCALE);
            f[4]=(short)f2bf(y.x*QSCALE); f[5]=(short)f2bf(y.y*QSCALE); f[6]=(short)f2bf(y.z*QSCALE); f[7]=(short)f2bf(y.w*QSCALE);
            qf[ks] = f;
        }
    }

    // ======== phase 0: compressed branch + top-k select (identical to R19) ========
    float* sc   = smemf;                   // [16][132] f32
    float* pgb  = smemf + 16 * 132;        // [2][128]
    float* adjb = smemf + 16 * 132 + 256;  // [2][32]

    // 0a: scores — wave owns 4 rows; each ck 64B load feeds 4 rows; 8 n's/pass
    {
        int ds = ln & 7, ng = ln >> 3;
        int d0 = ds * 16;
        float4 qr[4][4];
        #pragma unroll
        for (int rr = 0; rr < 4; ++rr) {
            int row = wv * 4 + rr;
            const float4* qp = reinterpret_cast<const float4*>(
                q + (tp + (row >> 3)) * 1024 + (row & 7) * 128 + d0);
            #pragma unroll
            for (int cc = 0; cc < 4; ++cc) qr[rr][cc] = qp[cc];
        }
        #pragma unroll 2
        for (int pass = 0; pass < 16; ++pass) {
            int n = pass * 8 + ng;
            if (n >= NCMP) continue;
            const float4* kp = reinterpret_cast<const float4*>(ck + n * 128 + d0);
            float4 k0 = kp[0], k1 = kp[1], k2 = kp[2], k3 = kp[3];
            float part[4];
            #pragma unroll
            for (int rr = 0; rr < 4; ++rr)
                part[rr] = dot4(qr[rr][0], k0) + dot4(qr[rr][1], k1) +
                           dot4(qr[rr][2], k2) + dot4(qr[rr][3], k3);
            #pragma unroll
            for (int off = 1; off < 8; off <<= 1)
                #pragma unroll
                for (int rr = 0; rr < 4; ++rr) part[rr] += __shfl_xor(part[rr], off);
            if (ds == 0) {
                #pragma unroll
                for (int rr = 0; rr < 4; ++rr)
                    sc[(wv * 4 + rr) * 132 + n] = part[rr] * SCALE;
            }
        }
    }
    __syncthreads();
    // 0b: masked softmax per row (16 lanes/row)
    {
        int r = tid >> 4, nl = tid & 15;
        int t = tp + (r >> 3);
        int nvalid = (t >= 31) ? (((t - 31) >> 4) + 1) : 0;
        if (nvalid > NCMP) nvalid = NCMP;
        float* row = sc + r * 132;
        float m = -3e38f;
        for (int n = nl; n < nvalid; n += 16) m = fmaxf(m, row[n]);
        m = fmaxf(m, __shfl_xor(m, 1));
        m = fmaxf(m, __shfl_xor(m, 2));
        m = fmaxf(m, __shfl_xor(m, 4));
        m = fmaxf(m, __shfl_xor(m, 8));
        float ss = 0.f;
        for (int n = nl; n < 128; n += 16) {
            float e = (n < nvalid) ? expf(row[n] - m) : 0.f;
            ss += e;
            row[n] = e;
        }
        ss += __shfl_xor(ss, 1);
        ss += __shfl_xor(ss, 2);
        ss += __shfl_xor(ss, 4);
        ss += __shfl_xor(ss, 8);
        float inv = (ss > 0.f) ? 1.f / ss : 0.f;
        for (int n = nl; n < 128; n += 16) row[n] *= inv;
    }
    __syncthreads();
    // 0c: head-sum pg
    {
        int tl = tid >> 7, n = tid & 127;
        if (n < NCMP) {
            float s = 0.f;
            #pragma unroll
            for (int h = 0; h < 8; ++h) s += sc[(tl * 8 + h) * 132 + n];
            pgb[tl * 128 + n] = s;
        }
    }
    __syncthreads();
    // 0d: select-block scores + causal/forced adjust
    if (tid < 64) {
        int tl = tid >> 5, s32 = tid & 31;
        float s = 0.f;
        #pragma unroll
        for (int j = 0; j < 4; ++j) {
            int n = s32 * 4 + j;
            if (n < NCMP) s += pgb[tl * 128 + n];
        }
        int qblk = (tp + tl) >> 6;
        adjb[tl * 32 + s32] = (s32 > qblk) ? -1e30f
                            : s + ((s32 == 0 || s32 > qblk - 2) ? 1e30f : 0.f);
    }
    __syncthreads();
    // 0e: wave0 top-16; all waves compute o_cmp (cv load shared across 4 rows)
    if (wv == 0) {
        int grp = ln >> 5, s32 = ln & 31;
        float val = adjb[grp * 32 + s32];
        unsigned int msk = 0u;
        for (int it = 0; it < 16; ++it) {
            float bv = val; int bi = s32;
            #pragma unroll
            for (int off = 1; off < 32; off <<= 1) {
                float ov = __shfl_xor(bv, off);
                int oi = __shfl_xor(bi, off);
                if (ov > bv || (ov == bv && oi < bi)) { bv = ov; bi = oi; }
            }
            if (bv <= -5e29f) break;
            msk |= 1u << bi;
            if (s32 == bi) val = -2e38f;
        }
        if (s32 == 0) selm[grp] = msk;
    }
    {
        int d = ln * 2;
        int t = tp + (wv >> 1);
        int nv = (t >= 31) ? (((t - 31) >> 4) + 1) : 0;
        if (nv > NCMP) nv = NCMP;
        float a0[4] = {0.f, 0.f, 0.f, 0.f};
        float a1[4] = {0.f, 0.f, 0.f, 0.f};
        const float* scb = sc + (wv * 4) * 132;
        for (int n = 0; n < nv; ++n) {
            float2 vvv = *reinterpret_cast<const float2*>(cv + n * 128 + d);
            #pragma unroll
            for (int rr = 0; rr < 4; ++rr) {
                float p = scb[rr * 132 + n];
                a0[rr] += p * vvv.x;
                a1[rr] += p * vvv.y;
            }
        }
        #pragma unroll
        for (int rr = 0; rr < 4; ++rr) {
            unsigned int wrd = (unsigned int)f2bf(a0[rr]) | ((unsigned int)f2bf(a1[rr]) << 16);
            *reinterpret_cast<unsigned int*>(&ocmp[(wv * 4 + rr) * 136 + d]) = wrd;
        }
    }
    __syncthreads();
    unsigned int sm0 = selm[0], sm1 = selm[1];

    // ======== block loop: both branch waves compute EVERY active block (half positions each) ========
    unsigned int sm_wave = sm0 | sm1;
    unsigned int smc = (c >> 3) ? sm1 : sm0;

    float m_run = -1e30f, l_run = 0.f;
    f32x4 o_acc[8];
    #pragma unroll
    for (int dt = 0; dt < 8; ++dt) o_acc[dt] = (f32x4){0.f, 0.f, 0.f, 0.f};

    int qblk_max = (tp + 1) >> 6;
    int wlo = (tp >= 575) ? (((tp - 575) >> 6) + 1) : 0;
    unsigned int all = (qblk_max >= 31) ? 0xFFFFFFFFu : ((1u << (qblk_max + 1)) - 1u);
    unsigned int wmask = all & ~((1u << wlo) - 1u);
    unsigned int mm = (sm_wave & all) | wmask;

    int srcA = ((g & 1) << 5) + c;
    int srcB = srcA + 16;
    bool hi = (g >= 2);

    auto stage = [&](int b) {
        const char* ks = (const char*)kswz + b * 16384;
        const char* vs = (const char*)vswz + b * 16384;
        char* kd = smem;
        char* vd = smem + 16384;
        int lo = wv * 1024;
        int so = lo + ln * 16;
        #pragma unroll
        for (int j = 0; j < 4; ++j) {
            gload_lds16(ks + j * 4096 + so, kd + j * 4096 + lo);
            gload_lds16(vs + j * 4096 + so, vd + j * 4096 + lo);
        }
    };

    // compute this wave's position half [w*32, w*32+32) of block b
    auto compute = [&](int b) {
        const char* kl = smem;
        const char* vl = smem + 16384;
        int z = (c & 7) << 4;

        // QK^T swapped, 2 position-groups (nt_g = 2w, 2w+1)
        f32x4 sacc[2];
        #pragma unroll
        for (int nt = 0; nt < 2; ++nt) {
            int ntg = 2 * w + nt;
            f32x4 acc = (f32x4){0.f, 0.f, 0.f, 0.f};
            #pragma unroll
            for (int ks = 0; ks < 4; ++ks) {
                bf16x8 kf = *reinterpret_cast<const bf16x8*>(
                    kl + (ntg * 16 + c) * 256 + ((ks * 64 + g * 16) ^ z));
                acc = __builtin_amdgcn_mfma_f32_16x16x32_bf16(kf, qf[ks], acc, 0, 0, 0);
            }
            sacc[nt] = acc;
        }

        bool selbit = (smc >> b) & 1u;
        float mloc = -1e30f;
        #pragma unroll
        for (int nt = 0; nt < 2; ++nt) {
            int ntg = 2 * w + nt;
            #pragma unroll
            for (int i = 0; i < 4; ++i) {
                int pos = b * 64 + ntg * 16 + g * 4 + i;
                bool val;
                if (is_sel) val = selbit && (pos <= th);
                else        val = (pos <= th) && (pos + 512 > th);
                float s = val ? sacc[nt][i] : -1e30f;
                sacc[nt][i] = s;
                mloc = fmaxf(mloc, s);
            }
        }
        mloc = fmaxf(mloc, __shfl_xor(mloc, 16));
        mloc = fmaxf(mloc, __shfl_xor(mloc, 32));
        float mn = fmaxf(m_run, mloc);
        float al = exp2f(m_run - mn);

        float lsum = 0.f;
        #pragma unroll
        for (int nt = 0; nt < 2; ++nt) {
            #pragma unroll
            for (int i = 0; i < 4; ++i) {
                float s = sacc[nt][i];
                float p = (s > -5e29f) ? exp2f(s - mn) : 0.f;
                sacc[nt][i] = p;
                lsum += p;
            }
        }
        lsum += __shfl_xor(lsum, 16);
        lsum += __shfl_xor(lsum, 32);
        m_run = mn;
        l_run = l_run * al + lsum;

        if (__any(al != 1.f)) {
            #pragma unroll
            for (int dt = 0; dt < 8; ++dt)
                #pragma unroll
                for (int i = 0; i < 4; ++i)
                    o_acc[dt][i] *= al;
        }

        // pack P (32 positions -> 4 words)
        unsigned int pw[4];
        #pragma unroll
        for (int nt = 0; nt < 2; ++nt) {
            unsigned int w0, w1;
            asm("v_cvt_pk_bf16_f32 %0, %1, %2" : "=v"(w0) : "v"(sacc[nt][0]), "v"(sacc[nt][1]));
            asm("v_cvt_pk_bf16_f32 %0, %1, %2" : "=v"(w1) : "v"(sacc[nt][2]), "v"(sacc[nt][3]));
            pw[2 * nt] = w0;
            pw[2 * nt + 1] = w1;
        }

        // PV: single k-slice (= this wave's position half)
        {
            unsigned int a0 = __shfl(pw[0], srcA);
            unsigned int a1 = __shfl(pw[1], srcA);
            unsigned int a2 = __shfl(pw[0], srcB);
            unsigned int a3 = __shfl(pw[1], srcB);
            unsigned int b0 = __shfl(pw[2], srcA);
            unsigned int b1 = __shfl(pw[3], srcA);
            unsigned int b2 = __shfl(pw[2], srcB);
            unsigned int b3 = __shfl(pw[3], srcB);
            unsigned int wparr[4] = {hi ? b0 : a0, hi ? b1 : a1, hi ? b2 : a2, hi ? b3 : a3};
            bf16x8 pa = *reinterpret_cast<bf16x8*>(wparr);
            #pragma unroll
            for (int dt = 0; dt < 8; ++dt) {
                bf16x8 vfr = *reinterpret_cast<const bf16x8*>(
                    vl + (dt * 16 + c) * 128 + ((w * 64 + g * 16) ^ z));
                o_acc[dt] = __builtin_amdgcn_mfma_f32_16x16x32_bf16(vfr, pa, o_acc[dt], 0, 0, 0);
            }
        }
    };

    while (mm) {
        int b = __builtin_ctz(mm);
        mm &= mm - 1;
        stage(b);
        __syncthreads();
        bool act = is_sel ? (((sm_wave >> b) & 1u) != 0u)
                          : (b * 64 + 575 > tp);
        if (act) compute(b);
        __syncthreads();
    }

    // ---- merge: wave1 -> wave0 (select halves), wave3 -> wave2 (window halves) ----
    float* mrgf = smemf;
    if (w == 1) {
        if (g == 0) { mlbuf[wv][c][0] = m_run; mlbuf[wv][c][1] = l_run; }
        float* dst = mrgf + (wv >> 1) * (16 * 132) + c * 132;
        #pragma unroll
        for (int dt = 0; dt < 8; ++dt)
            *reinterpret_cast<float4*>(dst + dt * 16 + g * 4) =
                (float4){o_acc[dt][0], o_acc[dt][1], o_acc[dt][2], o_acc[dt][3]};
    }
    __syncthreads();
    if (w == 0) {
        float m1 = mlbuf[wv + 1][c][0];
        float l1 = mlbuf[wv + 1][c][1];
        float mn = fmaxf(m_run, m1);
        float a0 = exp2f(m_run - mn), a1 = exp2f(m1 - mn);
        l_run = a0 * l_run + a1 * l1;
        float inv = 1.f / l_run;
        const float* src = mrgf + (wv >> 1) * (16 * 132) + c * 132;
        #pragma unroll
        for (int dt = 0; dt < 8; ++dt) {
            float4 o1 = *reinterpret_cast<const float4*>(src + dt * 16 + g * 4);
            o_acc[dt][0] = (a0 * o_acc[dt][0] + a1 * o1.x) * inv;
            o_acc[dt][1] = (a0 * o_acc[dt][1] + a1 * o1.y) * inv;
            o_acc[dt][2] = (a0 * o_acc[dt][2] + a1 * o1.z) * inv;
            o_acc[dt][3] = (a0 * o_acc[dt][3] + a1 * o1.w) * inv;
        }
    }
    if (wv == 2) {
        float* dst = mrgf + (16 * 132) + c * 132;
        #pragma unroll
        for (int dt = 0; dt < 8; ++dt)
            *reinterpret_cast<float4*>(dst + dt * 16 + g * 4) =
                (float4){o_acc[dt][0], o_acc[dt][1], o_acc[dt][2], o_acc[dt][3]};
    }
    __syncthreads();
    if (wv != 0) return;

    // ---- fusion epilogue ----
    const float* owp = mrgf + (16 * 132) + c * 132;
    float4 oc[8], ow[8];
    #pragma unroll
    for (int dt = 0; dt < 8; ++dt) {
        int d = dt * 16 + g * 4;
        oc[dt] = (float4){bf2f(ocmp[c * 136 + d]), bf2f(ocmp[c * 136 + d + 1]),
                          bf2f(ocmp[c * 136 + d + 2]), bf2f(ocmp[c * 136 + d + 3])};
        ow[dt] = *reinterpret_cast<const float4*>(owp + dt * 16 + g * 4);
    }
    const float* fwp = fw + hh * 3 * 384;
    float p0 = 0.f, p1 = 0.f, p2 = 0.f;
    #pragma unroll
    for (int dt = 0; dt < 8; ++dt) {
        #pragma unroll
        for (int i = 0; i < 4; ++i) {
            int d = dt * 16 + g * 4 + i;
            float a = (i == 0) ? oc[dt].x : (i == 1) ? oc[dt].y : (i == 2) ? oc[dt].z : oc[dt].w;
            float bsl = o_acc[dt][i];
            float cw = (i == 0) ? ow[dt].x : (i == 1) ? ow[dt].y : (i == 2) ? ow[dt].z : ow[dt].w;
            p0 += fwp[0 * 384 + d] * a + fwp[0 * 384 + 128 + d] * bsl + fwp[0 * 384 + 256 + d] * cw;
            p1 += fwp[1 * 384 + d] * a + fwp[1 * 384 + 128 + d] * bsl + fwp[1 * 384 + 256 + d] * cw;
            p2 += fwp[2 * 384 + d] * a + fwp[2 * 384 + 128 + d] * bsl + fwp[2 * 384 + 256 + d] * cw;
        }
    }
    p0 += __shfl_xor(p0, 16); p0 += __shfl_xor(p0, 32);
    p1 += __shfl_xor(p1, 16); p1 += __shfl_xor(p1, 32);
    p2 += __shfl_xor(p2, 16); p2 += __shfl_xor(p2, 32);
    float mx = fmaxf(p0, fmaxf(p1, p2));
    float e0 = expf(p0 - mx), e1 = expf(p1 - mx), e2 = expf(p2 - mx);
    float inv3 = 1.f / (e0 + e1 + e2);
    float w0 = e0 * inv3, w1 = e1 * inv3, w2 = e2 * inv3;
    #pragma unroll
    for (int dt = 0; dt < 8; ++dt) {
        float4 r;
        r.x = w0 * oc[dt].x + w1 * o_acc[dt][0] + w2 * ow[dt].x;
        r.y = w0 * oc[dt].y + w1 * o_acc[dt][1] + w2 * ow[dt].y;
        r.z = w0 * oc[dt].z + w1 * o_acc[dt][2] + w2 * ow[dt].z;
        r.w = w0 * oc[dt].w + w1 * o_acc[dt][3] + w2 * ow[dt].w;
        *reinterpret_cast<float4*>(out + th * 1024 + hh * 128 + dt * 16 + g * 4) = r;
    }
}

extern "C" void kernel_launch(void* const* d_in, const int* in_sizes, int n_in,
                              void* d_out, int out_size, void* d_ws, size_t ws_size,
                              hipStream_t stream) {
    (void)in_sizes; (void)n_in; (void)out_size; (void)ws_size;
    const float* q   = (const float*)d_in[0];
    const float* k   = (const float*)d_in[1];
    const float* v   = (const float*)d_in[2];
    const float* wk  = (const float*)d_in[3];
    const float* wvg = (const float*)d_in[4];
    const float* fw  = (const float*)d_in[5];
    float* out = (float*)d_out;
    float* ws = (float*)d_ws;
    float* ck = ws;
    float* cv = ws + NCMP * 128;
    unsigned short* kswz = (unsigned short*)(ws + 2 * NCMP * 128 + 2048);
    unsigned short* vswz = kswz + 2048 * 128;

    k_prep<<<dim3(64 + 2 * NCMP), dim3(256), 0, stream>>>(k, v, wk, wvg, ck, cv, kswz, vswz);
    k_main<<<dim3(1024), dim3(256), 0, stream>>>(q, ck, cv, kswz, vswz, fw, out);
}